// Round 10
// baseline (84.599 us; speedup 1.0000x reference)
//
#include <hip/hip_runtime.h>
#include <hip/hip_bf16.h>

// MultiHeadLiftLayer, R10 = R9 node_proj (vectorized, ~3us) + edge kernel
// with flat layout + NT stores (R8 win) + 4-way INDEPENDENT unroll:
// 4 load/store pairs in flight per wave (was MLP~1: each grid-stride
// iteration's store waited on its own load). Branch conditions are pure
// index math, so all 4 loads issue before the first s_waitcnt.
// If neutral: ~4.4 TB/s mixed-stream is the memory-system ceiling -> declare.

typedef float f4v __attribute__((ext_vector_type(4)));

#define NUM_NODES 50000
#define C0 128
#define HEADS 8
#define NPB 32                   // nodes per block (node_proj)
#define XSP 33                   // 32 f4 + 1 pad (f4 units)
#define EBLOCKS 8192

__global__ __launch_bounds__(256) void node_proj_kernel(
    const float* __restrict__ x0, const float* __restrict__ W,
    float* __restrict__ y, int num_nodes)
{
    __shared__ float Ws[2 * C0 * HEADS];   // 8 KB, W row-major [256][8]
    __shared__ f4v   xs4[NPB * XSP];       // 16.9 KB, padded rows of 32 f4

    {
        const f4v* __restrict__ Wv = (const f4v*)W;
        f4v* Wsv = (f4v*)Ws;
        Wsv[threadIdx.x]       = Wv[threadIdx.x];
        Wsv[threadIdx.x + 256] = Wv[threadIdx.x + 256];
    }

    const int nodeBase = blockIdx.x * NPB;
    const f4v* __restrict__ x0v = (const f4v*)x0;   // 32 f4 per node row
    #pragma unroll
    for (int k = 0; k < 4; ++k) {
        const int idx = k * 256 + threadIdx.x;
        const int r   = idx >> 5;
        const int c   = idx & 31;
        const int n   = nodeBase + r;
        f4v v = {0.f, 0.f, 0.f, 0.f};
        if (n < num_nodes) v = x0v[n * 32 + c];
        xs4[r * XSP + c] = v;
    }
    __syncthreads();

    const int slot  = threadIdx.x & 15;    // half*8 + h
    const int local = threadIdx.x >> 4;
    const int half  = slot >> 3;
    const int h     = slot & 7;

    const f4v* xr0 = &xs4[local * XSP];
    const f4v* xr1 = &xs4[(local + 16) * XSP];
    const float* Wb = &Ws[half * C0 * HEADS + h];

    float acc0 = 0.f, acc1 = 0.f;
    #pragma unroll 4
    for (int cq = 0; cq < 32; ++cq) {
        const f4v xq0 = xr0[cq];
        const f4v xq1 = xr1[cq];
        #pragma unroll
        for (int k = 0; k < 4; ++k) {
            const float w = Wb[(cq * 4 + k) * HEADS];
            acc0 = fmaf(xq0[k], w, acc0);
            acc1 = fmaf(xq1[k], w, acc1);
        }
    }

    const int n0 = nodeBase + local;
    const int n1 = n0 + 16;
    if (n0 < num_nodes) y[half * (NUM_NODES * HEADS) + n0 * HEADS + h] = acc0;
    if (n1 < num_nodes) y[half * (NUM_NODES * HEADS) + n1 * HEADS + h] = acc1;
}

static __device__ __forceinline__ f4v relu4(f4v a, f4v b) {
    f4v r;
    r.x = fmaxf(a.x + b.x, 0.f);
    r.y = fmaxf(a.y + b.y, 0.f);
    r.z = fmaxf(a.z + b.z, 0.f);
    r.w = fmaxf(a.w + b.w, 0.f);
    return r;
}

static __device__ __forceinline__ f4v merge_item(
    const f4v* __restrict__ y0v, const f4v* __restrict__ y1v,
    const f4v* __restrict__ x1v, const int* __restrict__ adj,
    int E, int i)
{
    const int e = i / 18;                  // magic-mul
    const int j = i - e * 18;
    if (j >= 2) {
        return x1v[e * 16 + (j - 2)];
    } else {
        const int s = adj[e];
        const int t = adj[E + e];
        return relu4(y0v[s * 2 + j], y1v[t * 2 + j]);
    }
}

__global__ __launch_bounds__(256) void edge_out_kernel(
    const float* __restrict__ y, const float* __restrict__ x1,
    const int* __restrict__ adj, float* __restrict__ out, int E)
{
    const f4v* __restrict__ y0v = (const f4v*)y;           // 2 f4 per node
    const f4v* __restrict__ y1v = y0v + 2 * NUM_NODES;
    const f4v* __restrict__ x1v = (const f4v*)x1;          // 16 f4 per edge
    f4v* __restrict__ outv = (f4v*)out;                    // 18 f4 per edge

    const int total  = E * 18;
    const int stride = EBLOCKS * 256;
    int i = blockIdx.x * 256 + threadIdx.x;

    // 4 independent load/store pairs in flight per wave
    for (; i + 3 * stride < total; i += 4 * stride) {
        const f4v v0 = merge_item(y0v, y1v, x1v, adj, E, i);
        const f4v v1 = merge_item(y0v, y1v, x1v, adj, E, i + stride);
        const f4v v2 = merge_item(y0v, y1v, x1v, adj, E, i + 2 * stride);
        const f4v v3 = merge_item(y0v, y1v, x1v, adj, E, i + 3 * stride);
        __builtin_nontemporal_store(v0, &outv[i]);
        __builtin_nontemporal_store(v1, &outv[i + stride]);
        __builtin_nontemporal_store(v2, &outv[i + 2 * stride]);
        __builtin_nontemporal_store(v3, &outv[i + 3 * stride]);
    }
    for (; i < total; i += stride)
        __builtin_nontemporal_store(merge_item(y0v, y1v, x1v, adj, E, i), &outv[i]);
}

extern "C" void kernel_launch(void* const* d_in, const int* in_sizes, int n_in,
                              void* d_out, int out_size, void* d_ws, size_t ws_size,
                              hipStream_t stream) {
    const float* x0  = (const float*)d_in[0];
    const int*   adj = (const int*)d_in[1];   // JAX demotes int64->int32
    const float* x1  = (const float*)d_in[2];
    const float* W   = (const float*)d_in[3];
    float* out = (float*)d_out;
    float* y   = (float*)d_ws;                // 2 * 50000*8 floats = 3.2 MB

    const int E = in_sizes[1] / 2;            // 625000

    {
        dim3 grid((NUM_NODES + NPB - 1) / NPB);   // 1563
        node_proj_kernel<<<grid, 256, 0, stream>>>(x0, W, y, NUM_NODES);
    }
    {
        edge_out_kernel<<<EBLOCKS, 256, 0, stream>>>(y, x1, adj, out, E);
    }
}